// Round 11
// baseline (237.244 us; speedup 1.0000x reference)
//
#include <hip/hip_runtime.h>

// MNIST_RNN R18: fence-free BODY. R17 post-mortem: flat vs R15 (120 vs
// 117us; DS cut offset by +8 MFMA). KEY CALIBRATION: MFMA work/wave
// (1568 x 4.85cyc) at MfmaUtil 8.5% => wall ~89k cyc/wave => effective
// clock ~730 MHz (not 2400; R9/R15 back-compute the same). Per-BODY
// ~3.2k cyc: issue ~1.9k (160 quarter-rate transcendentals ~1.3k = the
// VALUBusy bulk), idle ~1.3k of dependency latency. At 1 wave/SIMD the
// only filler is compiler interleave of the two streams - and the 3
// FENCEs/BODY forbid it (they exist because u32/u16 stores vs short8
// loads are different TBAA types). Fix: may_alias on LDS loads (loads
// then alias ALL stores -> program order of every store->load pair is
// preserved: WRH(1)@t-1 < RDA(1)@t, RDA < XWRITE), and DELETE both
// intra-BODY fences (keep one at BODY end to bound reg pressure).
// Zero numeric change; pure scheduling freedom.
// Watch: VGPR>256+scratch => spill, re-add R2|R3 fence only.

#define HDIM 10
#define DDIM 28
#define TSTEPS 28
#define NX 14          // x elements per lane (32*28/64)
#define STR 168        // panel row stride (shorts); 16B-aligned
// zone offsets within a row
#define ZH0P 56
#define ZH1P 76
#define ZH0H 96
#define ZH1H 106
#define ZXH  116
#define ZPAD 144

typedef __attribute__((ext_vector_type(8))) short short8;
typedef short8 __attribute__((may_alias)) short8a;        // LDS loads
typedef unsigned __attribute__((may_alias)) u32a;         // LDS b32 stores
typedef unsigned short __attribute__((may_alias)) u16a;   // LDS b16 stores
typedef __attribute__((ext_vector_type(4))) float f32x4;

__device__ __forceinline__ unsigned short bf16_rne(float f) {
    unsigned u = __builtin_bit_cast(unsigned, f);
    u += 0x7FFFu + ((u >> 16) & 1u);
    return (unsigned short)(u >> 16);
}
__device__ __forceinline__ float bf16_f(unsigned short h) {
    unsigned u = ((unsigned)h) << 16;
    return __builtin_bit_cast(float, u);
}
// packed {lo:hi} bf16 split of v: low16 = bf16_rne(v), high16 = bf16_rne(v - hi)
__device__ __forceinline__ unsigned pk_hl(float v) {
    unsigned a, p;
    const float z = 0.0f;
    asm("v_cvt_pk_bf16_f32 %0, %1, %2" : "=v"(a) : "v"(v), "v"(z));
    const float hif = __builtin_bit_cast(float, a << 16);
    const float d = v - hif;
    asm("v_cvt_pk_bf16_f32 %0, %1, %2" : "=v"(p) : "v"(v), "v"(d));
    return p;
}
__device__ __forceinline__ float sig_f(float v) {
    return __builtin_amdgcn_rcpf(1.0f + __expf(-v));
}
__device__ __forceinline__ float tanh_f(float v) {
    return 2.0f * __builtin_amdgcn_rcpf(1.0f + __expf(-2.0f * v)) - 1.0f;
}

#define FENCE() __asm volatile("" ::: "memory")
#define WR32(arrp, sidx, val) (*(u32a*)&(arrp)[(sidx)] = (val))
#define WR16(arrp, sidx, val) (*(u16a*)&(arrp)[(sidx)] = (val))

// ---- per-stream building blocks (MH = 0 or 1, compile-time) ----

// read A-fragments for stream MH (rows 16*MH + lm)
#define RDA(MH) do {                                                          \
    _Pragma("unroll")                                                         \
    for (int c = 0; c < 2; ++c)                                               \
        A1f[MH][c] = *(const short8a*)&uAw[(16 * (MH) + lm) * STR + ZH0P + 32 * c + 8 * q]; \
    _Pragma("unroll")                                                         \
    for (int c = 0; c < 5; ++c)                                               \
        A0f[MH][c] = *(const short8a*)&uAw[(16 * (MH) + lm) * STR + 32 * c + 8 * q]; \
} while (0)

// MFMA + act + cell update for stream MH -> h0v[MH], h1v[MH]
#define CMP(MH) do {                                                          \
    f32x4 C_[4], D_[4];                                                       \
    _Pragma("unroll")                                                         \
    for (int T4 = 0; T4 < 4; ++T4) {                                          \
        f32x4 accD = {bias1[T4], bias1[T4], bias1[T4], bias1[T4]};            \
        _Pragma("unroll")                                                     \
        for (int c = 0; c < 2; ++c)                                           \
            accD = __builtin_amdgcn_mfma_f32_16x16x32_bf16(A1f[MH][c], B1[T4][c], accD, 0, 0, 0); \
        D_[T4] = accD;                                                        \
        f32x4 accC = {bias0[T4], bias0[T4], bias0[T4], bias0[T4]};            \
        _Pragma("unroll")                                                     \
        for (int c = 0; c < 5; ++c)                                           \
            accC = __builtin_amdgcn_mfma_f32_16x16x32_bf16(A0f[MH][c], B0[T4][c], accC, 0, 0, 0); \
        C_[T4] = accC;                                                        \
    }                                                                         \
    _Pragma("unroll")                                                         \
    for (int r = 0; r < 4; ++r) {                                             \
        const float i1 = sig_f(D_[0][r]);                                     \
        const float f1 = sig_f(D_[1][r]);                                     \
        const float g1 = tanh_f(D_[2][r]);                                    \
        const float o1 = sig_f(D_[3][r]);                                     \
        const float c1 = f1 * c1s[MH][r] + i1 * g1;                           \
        c1s[MH][r] = c1;                                                      \
        h1v[MH][r] = o1 * tanh_f(c1);                                         \
        const float i0 = sig_f(C_[0][r]);                                     \
        const float f0 = sig_f(C_[1][r]);                                     \
        const float g0 = tanh_f(C_[2][r]);                                    \
        const float o0 = sig_f(C_[3][r]);                                     \
        const float c0 = f0 * c0s[MH][r] + i0 * g0;                           \
        c0s[MH][r] = c0;                                                      \
        h0v[MH][r] = o0 * tanh_f(c0);                                         \
    }                                                                         \
} while (0)

// write h1(t), h0(t+1) of stream MH back to the panel (single copy each)
#define WRH(MH) do {                                                          \
    if (lm < 10) {                                                            \
        _Pragma("unroll")                                                     \
        for (int r = 0; r < 4; ++r) {                                         \
            const int m = 16 * (MH) + 4 * q + r;                              \
            unsigned short* rw = &uAw[m * STR];                               \
            const unsigned p1 = pk_hl(h1v[MH][r]);                            \
            WR32(rw, ZH1P + 2 * lm, p1); WR16(rw, ZH1H + lm, (unsigned short)p1); \
            const unsigned p0 = pk_hl(h0v[MH][r]);                            \
            WR32(rw, ZH0P + 2 * lm, p0); WR16(rw, ZH0H + lm, (unsigned short)p0); \
        }                                                                     \
    }                                                                         \
} while (0)

// one macro-iteration (staggered, FENCE-FREE interior): cell1(T) +
// cell0(T+1) for both streams; mh1's h-writes deferred to next BODY.
// Correctness ordering is carried by DS program order (may_alias loads):
//   WRH(1)@T-1 < RDA(1)@T   (h zones, rows 16-31)
//   RDA(0),RDA(1)@T < XWRITE x(T+2) (pair zones)
//   WRH(0)@T < RDA(0)@T+1   (next BODY, after end-fence)
#define BODY(P, Q, T, FIRST) do {                                             \
    RDA(0);                                                                   \
    if (!(FIRST)) { WRH(1); }                                                 \
    if ((T) < TSTEPS - 3) {                                                   \
        _Pragma("unroll")                                                     \
        for (int i = 0; i < NX; ++i) { xoff[i] += DDIM; Q[i] = x[xoff[i]]; }  \
    }                                                                         \
    CMP(0);                                                                   \
    RDA(1);                                                                   \
    WRH(0);                                                                   \
    if ((T) < TSTEPS - 2) {                                                   \
        _Pragma("unroll")                                                     \
        for (int i = 0; i < NX; ++i) {                                        \
            const unsigned p = pk_hl(P[i]);                                   \
            WR32(uAw, lofsA[i], p);                                           \
            WR16(uAw, lofsB[i], (unsigned short)p);                           \
        }                                                                     \
    }                                                                         \
    CMP(1);                                                                   \
    FENCE();                                                                  \
} while (0)

__global__ __launch_bounds__(128, 1) void lstm2_mfma_kernel(
    const float* __restrict__ x,
    const float* __restrict__ w_ih0, const float* __restrict__ w_hh0,
    const float* __restrict__ b_ih0, const float* __restrict__ b_hh0,
    const float* __restrict__ w_ih1, const float* __restrict__ w_hh1,
    const float* __restrict__ b_ih1, const float* __restrict__ b_hh1,
    const float* __restrict__ w_cls, const float* __restrict__ b_cls,
    float* __restrict__ out)
{
    // 2 independent waves per block; per-wave private LDS; no barriers.
    // Unified panel row (stride 168 shorts):
    //   [ (x_d hi,lo) pairs d<28 : 0..55 | (h0 hi,lo) pairs : 56..75 |
    //     (h1 hi,lo) pairs : 76..95 | h0 hi : 96..105 | h1 hi : 106..115 |
    //     x_d hi : 116..143 | pad(0) : 144..167 ]      -- 32 rows
    // L0 operand: base 0, K=160 (B0 zero over 76..95,106..115,144..159).
    // L1 operand: base 56, K=64  (B1 zero over kk>=60 -> 116..119).
    __shared__ __align__(16) unsigned short uAs[2][32 * STR];
    __shared__ __align__(16) float hfins[2][32 * 12];

    const int l   = threadIdx.x & 63;
    const int wid = threadIdx.x >> 6;
    const int lm  = l & 15;
    const int q   = l >> 4;
    const int sbase = (blockIdx.x * 2 + wid) * 32;

    unsigned short* const uAw = uAs[wid];
    float* const hfinw = hfins[wid];

    // ---- zero pad zone (NaN*0=NaN in MFMA; L0 reads through 159) ----
    for (int i = l; i < 32 * 24; i += 64) uAw[(i / 24) * STR + ZPAD + (i % 24)] = 0;

    // ---- build B-fragments in registers (once; shared by both M-tiles) ----
    // 4 N-tiles: tile T row lm = gate g = 10T+lm (lm<10; rows lm>=10 zero).
    // T=0:i, T=1:f, T=2:g, T=3:o (torch gate order).
    short8 B0[4][5], B1[4][2];
    const bool gvalid = (lm < 10);
    #pragma unroll
    for (int T = 0; T < 4; ++T) {
        const int g = 10 * T + lm;
        #pragma unroll
        for (int c = 0; c < 5; ++c) {
            #pragma unroll
            for (int j = 0; j < 8; ++j) {
                const int kk = 32 * c + 8 * q + j;
                unsigned short bits = 0;
                if (gvalid) {
                    if (kk < ZH0P) {                     // x pairs -> w_ih0 hi
                        bits = bf16_rne(w_ih0[g * 28 + (kk >> 1)]);
                    } else if (kk < ZH1P) {              // h0 pairs -> w_hh0 hi
                        bits = bf16_rne(w_hh0[g * 10 + ((kk - ZH0P) >> 1)]);
                    } else if (kk < ZH0H) {              // h1 pairs: not L0 input
                        bits = 0;
                    } else if (kk < ZH1H) {              // h0 hi -> w_hh0 lo
                        const float w = w_hh0[g * 10 + (kk - ZH0H)];
                        const unsigned short hi = bf16_rne(w);
                        bits = bf16_rne(w - bf16_f(hi));
                    } else if (kk < ZXH) {               // h1 hi: not L0 input
                        bits = 0;
                    } else if (kk < ZPAD) {              // x hi -> w_ih0 lo
                        const float w = w_ih0[g * 28 + (kk - ZXH)];
                        const unsigned short hi = bf16_rne(w);
                        bits = bf16_rne(w - bf16_f(hi));
                    }
                }
                B0[T][c][j] = (short)bits;
            }
        }
        #pragma unroll
        for (int c = 0; c < 2; ++c) {
            #pragma unroll
            for (int j = 0; j < 8; ++j) {
                const int kk = 32 * c + 8 * q + j;   // position ZH0P + kk
                unsigned short bits = 0;
                if (gvalid && kk < 60) {
                    if (kk < 20) {                       // h0 pairs -> w_ih1 hi
                        bits = bf16_rne(w_ih1[g * 10 + (kk >> 1)]);
                    } else if (kk < 40) {                // h1 pairs -> w_hh1 hi
                        bits = bf16_rne(w_hh1[g * 10 + ((kk - 20) >> 1)]);
                    } else if (kk < 50) {                // h0 hi -> w_ih1 lo
                        const float w = w_ih1[g * 10 + (kk - 40)];
                        const unsigned short hi = bf16_rne(w);
                        bits = bf16_rne(w - bf16_f(hi));
                    } else {                             // h1 hi -> w_hh1 lo
                        const float w = w_hh1[g * 10 + (kk - 50)];
                        const unsigned short hi = bf16_rne(w);
                        bits = bf16_rne(w - bf16_f(hi));
                    }
                }
                B1[T][c][j] = (short)bits;
            }
        }
    }

    // biases folded into MFMA C-init
    float bias0[4], bias1[4];
    #pragma unroll
    for (int T = 0; T < 4; ++T) {
        const int g = 10 * T + lm;
        bias0[T] = gvalid ? (b_ih0[g] + b_hh0[g]) : 0.0f;
        bias1[T] = gvalid ? (b_ih1[g] + b_hh1[g]) : 0.0f;
    }

    // ---- x pipeline: lane owns NX=14 of the wave's 896 (sample,d) elems ----
    int xoff[NX], lofsA[NX], lofsB[NX];
    float xA[NX], xB[NX];
    #pragma unroll
    for (int i = 0; i < NX; ++i) {
        const int f = l + 64 * i;
        const int sm = f / 28, d = f - 28 * sm;
        lofsA[i] = sm * STR + 2 * d;        // b32 (pair zone)
        lofsB[i] = sm * STR + ZXH + d;      // b16 (hi zone)
        xoff[i] = (sbase + sm) * (TSTEPS * DDIM) + d;
        xA[i] = x[xoff[i]];                 // t = 0
    }
    #pragma unroll
    for (int i = 0; i < NX; ++i) {
        const unsigned p = pk_hl(xA[i]);
        WR32(uAw, lofsA[i], p);
        WR16(uAw, lofsB[i], (unsigned short)p);
    }
    // zero h zones (h0 = h1 = 0 at t=0)
    if (lm < 10) {
        #pragma unroll
        for (int mh = 0; mh < 2; ++mh) {
            #pragma unroll
            for (int r = 0; r < 4; ++r) {
                unsigned short* rw = &uAw[(16 * mh + 4 * q + r) * STR];
                WR32(rw, ZH0P + 2 * lm, 0u); WR16(rw, ZH0H + lm, 0);
                WR32(rw, ZH1P + 2 * lm, 0u); WR16(rw, ZH1H + lm, 0);
            }
        }
    }
    FENCE();

    float c0s[2][4] = {{0,0,0,0},{0,0,0,0}}, c1s[2][4] = {{0,0,0,0},{0,0,0,0}};
    float h1v[2][4] = {{0,0,0,0},{0,0,0,0}};
    float h0v[2][4];
    short8 A0f[2][5], A1f[2][2];

    // issue x(1) -> xA (consumed at end of prologue)
    #pragma unroll
    for (int i = 0; i < NX; ++i) { xoff[i] += DDIM; xA[i] = x[xoff[i]]; }

    // ================= prologue: cell0(0), both streams =================
    #pragma unroll
    for (int mh = 0; mh < 2; ++mh)
        #pragma unroll
        for (int c = 0; c < 5; ++c)
            A0f[mh][c] = *(const short8a*)&uAw[(16 * mh + lm) * STR + 32 * c + 8 * q];
    FENCE();
    // issue x(2) -> xB (consumed in main-loop body t=0)
    #pragma unroll
    for (int i = 0; i < NX; ++i) { xoff[i] += DDIM; xB[i] = x[xoff[i]]; }
    {
        f32x4 C[2][4];
        #pragma unroll
        for (int mh = 0; mh < 2; ++mh) {
            #pragma unroll
            for (int T = 0; T < 4; ++T) {
                f32x4 acc = {bias0[T], bias0[T], bias0[T], bias0[T]};
                #pragma unroll
                for (int c = 0; c < 5; ++c)
                    acc = __builtin_amdgcn_mfma_f32_16x16x32_bf16(A0f[mh][c], B0[T][c], acc, 0, 0, 0);
                C[mh][T] = acc;
            }
        }
        #pragma unroll
        for (int mh = 0; mh < 2; ++mh) {
            #pragma unroll
            for (int r = 0; r < 4; ++r) {
                const float i0 = sig_f(C[mh][0][r]);
                const float f0 = sig_f(C[mh][1][r]);
                const float g0 = tanh_f(C[mh][2][r]);
                const float o0 = sig_f(C[mh][3][r]);
                const float c0 = f0 * c0s[mh][r] + i0 * g0;
                c0s[mh][r] = c0;
                h0v[mh][r] = o0 * tanh_f(c0);
            }
        }
        if (lm < 10) {
            #pragma unroll
            for (int mh = 0; mh < 2; ++mh) {
                #pragma unroll
                for (int r = 0; r < 4; ++r) {
                    unsigned short* rw = &uAw[(16 * mh + 4 * q + r) * STR];
                    const unsigned p0 = pk_hl(h0v[mh][r]);
                    WR32(rw, ZH0P + 2 * lm, p0); WR16(rw, ZH0H + lm, (unsigned short)p0);
                }
            }
        }
        // write x(1) (xA loads issued well before)
        #pragma unroll
        for (int i = 0; i < NX; ++i) {
            const unsigned p = pk_hl(xA[i]);
            WR32(uAw, lofsA[i], p);
            WR16(uAw, lofsB[i], (unsigned short)p);
        }
    }
    FENCE();

    // ===== main loop: staggered fence-free bodies; x buffers alternate =====
    BODY(xB, xA, 0, 1);
    BODY(xA, xB, 1, 0);
    #pragma unroll 1
    for (int tp = 1; tp < 13; ++tp) {
        BODY(xB, xA, 2 * tp, 0);
        BODY(xA, xB, 2 * tp + 1, 0);
    }
    BODY(xB, xA, 26, 0);

    // mh1's deferred h-writes for T=26 (h1(26), h0(27))
    WRH(1);
    FENCE();

    // ================= epilogue: cell1(27), both streams =================
    {
        #pragma unroll
        for (int mh = 0; mh < 2; ++mh)
            #pragma unroll
            for (int c = 0; c < 2; ++c)
                A1f[mh][c] = *(const short8a*)&uAw[(16 * mh + lm) * STR + ZH0P + 32 * c + 8 * q];
        FENCE();
        f32x4 D[2][4];
        #pragma unroll
        for (int mh = 0; mh < 2; ++mh) {
            #pragma unroll
            for (int T = 0; T < 4; ++T) {
                f32x4 acc = {bias1[T], bias1[T], bias1[T], bias1[T]};
                #pragma unroll
                for (int c = 0; c < 2; ++c)
                    acc = __builtin_amdgcn_mfma_f32_16x16x32_bf16(A1f[mh][c], B1[T][c], acc, 0, 0, 0);
                D[mh][T] = acc;
            }
        }
        #pragma unroll
        for (int mh = 0; mh < 2; ++mh) {
            #pragma unroll
            for (int r = 0; r < 4; ++r) {
                const float i1 = sig_f(D[mh][0][r]);
                const float f1 = sig_f(D[mh][1][r]);
                const float g1 = tanh_f(D[mh][2][r]);
                const float o1 = sig_f(D[mh][3][r]);
                const float c1 = f1 * c1s[mh][r] + i1 * g1;
                h1v[mh][r] = o1 * tanh_f(c1);
            }
        }
    }

    // ---- classifier ----
    if (lm < 10) {
        #pragma unroll
        for (int mh = 0; mh < 2; ++mh)
            #pragma unroll
            for (int r = 0; r < 4; ++r)
                hfinw[(16 * mh + 4 * q + r) * 12 + lm] = h1v[mh][r];
    }
    FENCE();
    if (lm < 10) {
        float wc[10];
        #pragma unroll
        for (int j = 0; j < 10; ++j) wc[j] = w_cls[lm * 10 + j];
        const float bo = b_cls[lm];
        #pragma unroll
        for (int mh = 0; mh < 2; ++mh) {
            #pragma unroll
            for (int r = 0; r < 4; ++r) {
                const int m = 16 * mh + 4 * q + r;
                float acc = bo;
                #pragma unroll
                for (int j = 0; j < 10; ++j) acc += hfinw[m * 12 + j] * wc[j];
                out[(size_t)(sbase + m) * 10 + lm] = acc;
            }
        }
    }
}

extern "C" void kernel_launch(void* const* d_in, const int* in_sizes, int n_in,
                              void* d_out, int out_size, void* d_ws, size_t ws_size,
                              hipStream_t stream) {
    const float* x     = (const float*)d_in[0];
    const float* w_ih0 = (const float*)d_in[1];
    const float* w_hh0 = (const float*)d_in[2];
    const float* b_ih0 = (const float*)d_in[3];
    const float* b_hh0 = (const float*)d_in[4];
    const float* w_ih1 = (const float*)d_in[5];
    const float* w_hh1 = (const float*)d_in[6];
    const float* b_ih1 = (const float*)d_in[7];
    const float* b_hh1 = (const float*)d_in[8];
    const float* w_cls = (const float*)d_in[9];
    const float* b_cls = (const float*)d_in[10];
    float* out = (float*)d_out;

    const int B = in_sizes[0] / (TSTEPS * DDIM);   // 32768
    const int grid = B / 64;                       // 512 blocks x 2 waves x 32 samples

    hipLaunchKernelGGL(lstm2_mfma_kernel, dim3(grid), dim3(128), 0, stream,
                       x, w_ih0, w_hh0, b_ih0, b_hh0,
                       w_ih1, w_hh1, b_ih1, b_hh1,
                       w_cls, b_cls, out);
}